// Round 10
// baseline (96.811 us; speedup 1.0000x reference)
//
#include <hip/hip_runtime.h>

#define S_LEN 2048
#define EMB_D 1024
#define QK_SCALE 0.08838834764831845f  // 1/sqrt(128)
#define RS128 11.313708498984761f      // sqrt(128)
#define LOG2E 1.4426950408889634f

typedef _Float16 f16;
typedef f16 f16x8 __attribute__((ext_vector_type(8)));
typedef float f32x4 __attribute__((ext_vector_type(4)));
typedef unsigned short ushort_t;

typedef const __attribute__((address_space(1))) void gvoid;
typedef __attribute__((address_space(3))) void lvoid;

__device__ __forceinline__ ushort_t f2h(float x) {
    return __builtin_bit_cast(ushort_t, (f16)x);   // RNE
}
__device__ __forceinline__ unsigned pk2h(float a, float b) {
    return __builtin_bit_cast(unsigned, __builtin_amdgcn_cvt_pkrtz(a, b));
}
__device__ __forceinline__ void gl_lds(const void* g, void* l) {
    __builtin_amdgcn_global_load_lds((gvoid*)g, (lvoid*)l, 16, 0, 0);
}

// ---------------- kernel 1: W fp16 B-frag blobs. Wf[ks_g][lane][8], ks_g = src*32+hemb*4+ks.
// q-rows of W scaled by sqrt(128) (compensates QK_SCALE baked into staged q).
__global__ __launch_bounds__(256) void ktransW(const float* __restrict__ igk,
                                               const float* __restrict__ fgk,
                                               ushort_t* __restrict__ Wf) {
    int gid = blockIdx.x * 256 + threadIdx.x;  // 0..6143
    int ks_g = gid >> 6, lane = gid & 63;
    int n = lane & 15, lg = lane >> 4;
    int src = ks_g >> 5, rem = ks_g & 31;
    int hemb = rem >> 2, ks = rem & 3;
    int e0 = src * 1024 + hemb * 128 + ks * 32 + lg * 8;
    float scale = (src == 0) ? RS128 : 1.0f;
    const float* col = (n < 8) ? igk : fgk;
    int nn = n & 7;
    union { ushort_t u[8]; uint4 v4; } P;
    #pragma unroll
    for (int e = 0; e < 8; ++e) P.u[e] = f2h(col[(size_t)(e0 + e) * 8 + nn] * scale);
    *(uint4*)((char*)Wf + ks_g * 1024 + lane * 16) = P.v4;
}

// ---------------- kernel 2: fused split + gate GEMM. Block = (b, 16-row strip), 256 blocks.
// Loads q,k,v rows once; writes pre-swizzled Q/K fp16 tiles, Vt in [tile][joct][128d][8j]
// layout (coalesced B-frag reads later), and computes gate preacts via MFMA from LDS.
__global__ __launch_bounds__(256) void kprep(const float* __restrict__ q,
                                             const float* __restrict__ k,
                                             const float* __restrict__ v,
                                             const ushort_t* __restrict__ Wf,
                                             const float* __restrict__ igb,
                                             const float* __restrict__ fgb,
                                             ushort_t* __restrict__ Qf,
                                             ushort_t* __restrict__ Kf,
                                             ushort_t* __restrict__ Vt,
                                             float* __restrict__ igp_t,
                                             float* __restrict__ fgp_t) {
    __shared__ __align__(16) ushort_t xs[3 * 8 * 16 * 128];  // 96KB [src*8+h][16r][128c] swz
    __shared__ __align__(16) float red[4][64][4];
    const int blk = blockIdx.x;
    const int b = blk >> 7, strip = blk & 127;
    const int s0 = strip * 16;
    const int tile = strip >> 2, subrow = (strip & 3) * 16;
    const int t = threadIdx.x;
    const int w = t >> 6, lane = t & 63;
    const int ll = lane & 15, lg = lane >> 4;

    #pragma unroll
    for (int src = 0; src < 3; ++src) {
        const float* sp = (src == 0 ? q : src == 1 ? k : v) + ((size_t)b * S_LEN + s0) * EMB_D;
        float scale = (src == 0) ? QK_SCALE : 1.0f;
        #pragma unroll
        for (int i = 0; i < 16; ++i) {
            int f = i * 256 + t;
            int r = f >> 8, c4 = f & 255;
            int col = c4 * 4;
            float4 x = *(const float4*)(sp + (size_t)r * EMB_D + col);
            ushort4 H;
            H.x = f2h(x.x * scale); H.y = f2h(x.y * scale);
            H.z = f2h(x.z * scale); H.w = f2h(x.w * scale);
            int hh = col >> 7, d0 = col & 127;
            *(ushort4*)((char*)xs + ((((src * 8 + hh) * 16 + r) * 256 + d0 * 2) ^ ((r & 7) << 4))) = H;
            if (src < 2) {
                char* dst = (char*)(src ? Kf : Qf) + ((size_t)(b * 8 + hh) * 32 + tile) * 16384;
                *(ushort4*)(dst + (((subrow + r) * 256 + d0 * 2) ^ ((r & 7) << 4))) = H;
            }
        }
    }
    __syncthreads();
    // Vt transpose from LDS: [bh][tile][joct][128 d][8 j]
    #pragma unroll
    for (int it = 0; it < 8; ++it) {
        int item = it * 256 + t;           // 0..2047
        int d = item & 127, jo = (item >> 7) & 1, hh = item >> 8;
        union { ushort_t u[8]; uint4 v4; } P;
        #pragma unroll
        for (int e = 0; e < 8; ++e) {
            int r = jo * 8 + e;
            P.u[e] = *(const ushort_t*)((const char*)xs
                       + ((((16 + hh) * 16 + r) * 256 + d * 2) ^ ((r & 7) << 4)));
        }
        char* vd = (char*)Vt + ((size_t)(b * 8 + hh) * 32 + tile) * 16384
                 + ((strip & 3) * 2 + jo) * 2048 + d * 16;
        *(uint4*)vd = P.v4;
    }
    // gate GEMM: wave w does 6 of 24 (src,hemb) rounds; 4-way partial reduce via LDS
    f32x4 acc = {0.f, 0.f, 0.f, 0.f};
    for (int ri = w * 6; ri < w * 6 + 6; ++ri) {
        int src = ri >> 3, hemb = ri & 7;
        #pragma unroll
        for (int ks = 0; ks < 4; ++ks) {
            f16x8 af = *(const f16x8*)((const char*)xs
                        + ((((src * 8 + hemb) * 16 + ll) * 256 + ks * 64 + lg * 16) ^ ((ll & 7) << 4)));
            f16x8 bf = *(const f16x8*)((const char*)Wf + (src * 32 + hemb * 4 + ks) * 1024 + lane * 16);
            acc = __builtin_amdgcn_mfma_f32_16x16x32_f16(af, bf, acc, 0, 0, 0);
        }
    }
    *(f32x4*)&red[w][lane][0] = acc;
    __syncthreads();
    if (w == 0) {
        f32x4 o2 = acc;
        #pragma unroll
        for (int ww = 1; ww < 4; ++ww) o2 += *(const f32x4*)&red[ww][lane][0];
        float bias = (ll < 8) ? igb[ll] : fgb[ll - 8];
        float* dst = (ll < 8) ? igp_t : fgp_t;
        size_t ob = (size_t)(b * 8 + (ll & 7)) * S_LEN + s0 + lg * 4;
        #pragma unroll
        for (int r = 0; r < 4; ++r) dst[ob + r] = o2[r] + bias;
    }
}

// ---------------- kernel 3: per-(b,h) prefix scans, single wave, no barriers.
__global__ __launch_bounds__(64) void kscan(const float* __restrict__ igp_t,
                                            const float* __restrict__ fgp_t,
                                            float* __restrict__ a_w,
                                            float* __restrict__ pm_w,
                                            float* __restrict__ nf_w) {
    const int bh = blockIdx.x;
    const int l = threadIdx.x;
    const int base = bh * S_LEN + l * 32;
    float lf[32];
    #pragma unroll
    for (int i = 0; i < 8; ++i) {
        float4 fg = *(const float4*)(fgp_t + base + i * 4);
        float* p = &lf[i * 4];
        p[0] = fminf(fg.x, 0.f) - log1pf(__expf(-fabsf(fg.x)));
        p[1] = fminf(fg.y, 0.f) - log1pf(__expf(-fabsf(fg.y)));
        p[2] = fminf(fg.z, 0.f) - log1pf(__expf(-fabsf(fg.z)));
        p[3] = fminf(fg.w, 0.f) - log1pf(__expf(-fabsf(fg.w)));
    }
    #pragma unroll
    for (int i = 1; i < 32; ++i) lf[i] += lf[i - 1];
    float tot = lf[31];
    #pragma unroll
    for (int d = 1; d < 64; d <<= 1) {
        float n = __shfl_up(tot, d, 64);
        if (l >= d) tot += n;
    }
    float excl = tot - lf[31];
    float cs[32], a[32];
    #pragma unroll
    for (int i = 0; i < 8; ++i) {
        float4 ig = *(const float4*)(igp_t + base + i * 4);
        float iv[4] = {ig.x, ig.y, ig.z, ig.w};
        #pragma unroll
        for (int e = 0; e < 4; ++e) {
            int idx = i * 4 + e;
            cs[idx] = excl + lf[idx];
            a[idx] = iv[e] - cs[idx];
            a_w[base + idx] = a[idx] * LOG2E;
        }
    }
    float am[32];
    am[0] = a[0];
    #pragma unroll
    for (int i = 1; i < 32; ++i) am[i] = fmaxf(am[i - 1], a[i]);
    float mtot = am[31];
    #pragma unroll
    for (int d = 1; d < 64; d <<= 1) {
        float n = __shfl_up(mtot, d, 64);
        if (l >= d) mtot = fmaxf(mtot, n);
    }
    float exm = __shfl_up(mtot, 1, 64);
    if (l == 0) exm = -INFINITY;
    #pragma unroll
    for (int i = 0; i < 32; ++i) {
        float pmv = fmaxf(exm, am[i]);
        pm_w[base + i] = pmv * LOG2E;
        nf_w[base + i] = __expf(-(cs[i] + pmv));
    }
}

// ---------------- kernel 4: main core. 256 blocks x 512 thr (2 groups x 4 waves).
// amdgpu_waves_per_eu(2,2): pins allocator at 2 waves/SIMD -> 256-VGPR budget.
// (R8/R9: backend kept a 4-waves/SIMD target -> 128-VGPR cap -> ~60 VGPRs of the
// V/a register double-buffer spilled to scratch every superstep: +18-26MB traffic.)
// Block = (bh, pair): rt = pair then 31-pair (uniform 17 supersteps). Group g does
// ct = g, g+2,... K double-buffered in LDS (global_load_lds); V and a prefetched
// L2->REGISTERS one superstep ahead (coalesced via joct Vt layout); Cs via LDS.
// Mid-step barrier lgkm-only; vmcnt(0) only at superstep end (full-ss covered).
__global__ __attribute__((amdgpu_flat_work_group_size(512, 512), amdgpu_waves_per_eu(2, 2)))
void kmain(const ushort_t* __restrict__ Qf,
           const ushort_t* __restrict__ Kf,
           const ushort_t* __restrict__ Vt,
           const float* __restrict__ a_w,
           const float* __restrict__ pm_w,
           const float* __restrict__ nf_w,
           float* __restrict__ out) {
    __shared__ __align__(16) ushort_t Kbuf[2][2][8192];  // [group][dbuf] 64KB
    __shared__ __align__(16) ushort_t Csh[2][4096];      // [group] 16KB
    __shared__ float redL[2][2][64];

    const int blk = blockIdx.x;
    const int bh = blk & 15;             // XCD = blk%8 = bh&7 (matches kprep writes)
    const int pair = blk >> 4;           // 0..15
    const int b = bh >> 3, h = bh & 7;
    const int t = threadIdx.x;
    const int w = t >> 6, lane = t & 63;
    const int g = w >> 2, wl = w & 3;
    const int wr = wl >> 1, wc = wl & 1;
    const int lg = lane >> 4, ll = lane & 15;
    const int sw = (ll & 7) << 4;

    const char* q_b = (const char*)Qf + (size_t)bh * 524288;
    const char* k_b = (const char*)Kf + (size_t)bh * 524288;
    const char* v_b = (const char*)Vt + (size_t)bh * 524288;
    const float* aw = a_w + bh * S_LEN;

    float* accX = (float*)&Kbuf[0][0][0];   // 32KB combine region (post-loop alias)
    float* rsX  = (float*)&Csh[0][0];       // 2KB (post-loop alias)

    for (int half = 0; half < 2; ++half) {
        const int rt = half ? (31 - pair) : pair;
        const int row0 = rt * 64;
        const int nss = (rt >> 1) + 1;
        __syncthreads();   // previous half's LDS (incl combine aliases) done

        // Q frags direct from global pre-swizzled tile
        const char* qt = q_b + (size_t)rt * 16384;
        f16x8 qf[2][4];
        #pragma unroll
        for (int ib = 0; ib < 2; ++ib) {
            int row = 32 * wr + 16 * ib + ll;
            #pragma unroll
            for (int kk = 0; kk < 4; ++kk)
                qf[ib][kk] = *(const f16x8*)(qt + ((row * 256 + lg * 16 + kk * 64) ^ ((row & 7) << 4)));
        }
        float pm2[2];
        #pragma unroll
        for (int ib = 0; ib < 2; ++ib)
            pm2[ib] = pm_w[bh * S_LEN + row0 + 32 * wr + 16 * ib + ll];

        // stage K(g) into buf0; prefetch V(g), a(g) into regs
        f16x8 bvA[2][4], bvB[2][4];
        f32x4 avA[2] = {{0.f,0.f,0.f,0.f},{0.f,0.f,0.f,0.f}};
        f32x4 avB[2] = {{0.f,0.f,0.f,0.f},{0.f,0.f,0.f,0.f}};
        if (g <= rt) {
            const char* kt = k_b + (size_t)g * 16384;
            #pragma unroll
            for (int i = 0; i < 4; ++i) {
                int o = (wl * 4 + i) * 1024 + lane * 16;
                gl_lds(kt + o, (char*)&Kbuf[g][0][0] + o);
            }
            const char* vt = v_b + (size_t)g * 16384;
            #pragma unroll
            for (int kk = 0; kk < 2; ++kk)
                #pragma unroll
                for (int vf = 0; vf < 4; ++vf)
                    bvA[kk][vf] = *(const f16x8*)(vt + (kk * 4 + lg) * 2048 + (64 * wc + 16 * vf + ll) * 16);
            #pragma unroll
            for (int jb = 0; jb < 2; ++jb)
                avA[jb] = *(const f32x4*)(aw + g * 64 + 32 * wc + 16 * jb + 4 * lg);
        }
        asm volatile("s_waitcnt vmcnt(0)" ::: "memory");
        __builtin_amdgcn_s_barrier();

        f32x4 zero4 = {0.f, 0.f, 0.f, 0.f};
        f32x4 accO[2][4];
        #pragma unroll
        for (int ib = 0; ib < 2; ++ib)
            #pragma unroll
            for (int vf = 0; vf < 4; ++vf) accO[ib][vf] = zero4;
        float rs[2] = {0.f, 0.f};

        auto STEP = [&](int ssv, int P, f16x8 (&bvC)[2][4], f16x8 (&bvN)[2][4],
                        f32x4 (&avC)[2], f32x4 (&avN)[2]) {
            const int myct = 2 * ssv + g;
            const int nxct = myct + 2;
            if (nxct <= rt) {   // issue next staging (drains at END of this superstep)
                const char* kt = k_b + (size_t)nxct * 16384;
                #pragma unroll
                for (int i = 0; i < 4; ++i) {
                    int o = (wl * 4 + i) * 1024 + lane * 16;
                    gl_lds(kt + o, (char*)&Kbuf[g][P ^ 1][0] + o);
                }
                const char* vt = v_b + (size_t)nxct * 16384;
                #pragma unroll
                for (int kk = 0; kk < 2; ++kk)
                    #pragma unroll
                    for (int vf = 0; vf < 4; ++vf)
                        bvN[kk][vf] = *(const f16x8*)(vt + (kk * 4 + lg) * 2048 + (64 * wc + 16 * vf + ll) * 16);
                #pragma unroll
                for (int jb = 0; jb < 2; ++jb)
                    avN[jb] = *(const f32x4*)(aw + nxct * 64 + 32 * wc + 16 * jb + 4 * lg);
            }
            const bool act = (myct <= rt);
            if (act) {
                const char* kl = (const char*)&Kbuf[g][P][0];
                f32x4 accST[2][2];
                accST[0][0] = zero4; accST[0][1] = zero4;
                accST[1][0] = zero4; accST[1][1] = zero4;
                __builtin_amdgcn_s_setprio(1);
                #pragma unroll
                for (int kk = 0; kk < 4; ++kk) {
                    f16x8 kf0 = *(const f16x8*)(kl + (((32 * wc + ll) * 256 + lg * 16 + kk * 64) ^ sw));
                    f16x8 kf1 = *(const f16x8*)(kl + (((32 * wc + 16 + ll) * 256 + lg * 16 + kk * 64) ^ sw));
                    accST[0][0] = __builtin_amdgcn_mfma_f32_16x16x32_f16(kf0, qf[0][kk], accST[0][0], 0, 0, 0);
                    accST[0][1] = __builtin_amdgcn_mfma_f32_16x16x32_f16(kf0, qf[1][kk], accST[0][1], 0, 0, 0);
                    accST[1][0] = __builtin_amdgcn_mfma_f32_16x16x32_f16(kf1, qf[0][kk], accST[1][0], 0, 0, 0);
                    accST[1][1] = __builtin_amdgcn_mfma_f32_16x16x32_f16(kf1, qf[1][kk], accST[1][1], 0, 0, 0);
                }
                __builtin_amdgcn_s_setprio(0);
                const bool diag = (myct == rt);
                #pragma unroll
                for (int jb = 0; jb < 2; ++jb) {
                    #pragma unroll
                    for (int ib = 0; ib < 2; ++ib) {
                        int il = 32 * wr + 16 * ib + ll;
                        float cv[4];
                        #pragma unroll
                        for (int r = 0; r < 4; ++r) {
                            int jl = 32 * wc + 16 * jb + 4 * lg + r;
                            float x = accST[jb][ib][r] * exp2f(avC[jb][r] - pm2[ib]);
                            if (diag && jl > il) x = 0.f;
                            rs[ib] += x;
                            cv[r] = x;
                        }
                        int off = (il * 128 + (32 * wc + 16 * jb + 4 * lg) * 2) ^ ((il & 7) << 4);
                        uint2 pk2; pk2.x = pk2h(cv[0], cv[1]); pk2.y = pk2h(cv[2], cv[3]);
                        *(uint2*)((char*)&Csh[g][0] + off) = pk2;
                    }
                }
            }
            asm volatile("s_waitcnt lgkmcnt(0)" ::: "memory");
            __builtin_amdgcn_s_barrier();
            if (act) {
                __builtin_amdgcn_s_setprio(1);
                #pragma unroll
                for (int kk = 0; kk < 2; ++kk)
                    #pragma unroll
                    for (int ib = 0; ib < 2; ++ib) {
                        int rowA = 32 * wr + 16 * ib + ll;
                        f16x8 pa = *(const f16x8*)((const char*)&Csh[g][0]
                                                   + ((rowA * 128 + lg * 16 + kk * 64) ^ ((rowA & 7) << 4)));
                        #pragma unroll
                        for (int vf = 0; vf < 4; ++vf)
                            accO[ib][vf] = __builtin_amdgcn_mfma_f32_16x16x32_f16(pa, bvC[kk][vf], accO[ib][vf], 0, 0, 0);
                    }
                __builtin_amdgcn_s_setprio(0);
            }
            asm volatile("s_waitcnt vmcnt(0)" ::: "memory");
            __builtin_amdgcn_s_barrier();
        };

        for (int ss = 0; ss < nss; ss += 2) {
            STEP(ss, 0, bvA, bvB, avA, avB);
            if (ss + 1 < nss) STEP(ss + 1, 1, bvB, bvA, avB, avA);
        }

        // ---- combine the two groups' partials, then finalize (group0)
        __syncthreads();
        const int li = wl * 64 + lane;
        const int lsw = (li & 7) << 2;   // float-index XOR swizzle (16B granules)
        if (g == 1) {
            #pragma unroll
            for (int ib = 0; ib < 2; ++ib)
                #pragma unroll
                for (int vf = 0; vf < 4; ++vf)
                    *(f32x4*)&accX[(li * 32 + (ib * 4 + vf) * 4) ^ lsw] = accO[ib][vf];
            rsX[li * 2 + 0] = rs[0];
            rsX[li * 2 + 1] = rs[1];
        }
        __syncthreads();
        if (g == 0) {
            #pragma unroll
            for (int ib = 0; ib < 2; ++ib)
                #pragma unroll
                for (int vf = 0; vf < 4; ++vf)
                    accO[ib][vf] += *(const f32x4*)&accX[(li * 32 + (ib * 4 + vf) * 4) ^ lsw];
            rs[0] += rsX[li * 2 + 0];
            rs[1] += rsX[li * 2 + 1];
            #pragma unroll
            for (int ib = 0; ib < 2; ++ib) {
                rs[ib] += __shfl_xor(rs[ib], 16);
                rs[ib] += __shfl_xor(rs[ib], 32);
            }
            if (lg == 0) {
                redL[0][wc][32 * wr + ll] = rs[0];
                redL[0][wc][32 * wr + 16 + ll] = rs[1];
            }
        }
        __syncthreads();
        if (g == 0) {
            float invn[2][4];
            #pragma unroll
            for (int ib = 0; ib < 2; ++ib)
                #pragma unroll
                for (int r = 0; r < 4; ++r) {
                    int il = 32 * wr + 16 * ib + 4 * lg + r;
                    float tot = redL[0][0][il] + redL[0][1][il];
                    float nf = nf_w[bh * S_LEN + row0 + il];
                    invn[ib][r] = 1.0f / (fmaxf(fabsf(tot), nf) + 1e-6f);
                }
            float ssq[2][4] = {{0.f, 0.f, 0.f, 0.f}, {0.f, 0.f, 0.f, 0.f}};
            #pragma unroll
            for (int ib = 0; ib < 2; ++ib)
                #pragma unroll
                for (int vf = 0; vf < 4; ++vf)
                    #pragma unroll
                    for (int r = 0; r < 4; ++r) {
                        float hv = accO[ib][vf][r] * invn[ib][r];
                        ssq[ib][r] += hv * hv;
                    }
            #pragma unroll
            for (int m = 1; m < 16; m <<= 1)
                #pragma unroll
                for (int ib = 0; ib < 2; ++ib)
                    #pragma unroll
                    for (int r = 0; r < 4; ++r) ssq[ib][r] += __shfl_xor(ssq[ib][r], m);
            if (ll == 0) {
                #pragma unroll
                for (int ib = 0; ib < 2; ++ib)
                    #pragma unroll
                    for (int r = 0; r < 4; ++r)
                        redL[1][wc][32 * wr + 16 * ib + 4 * lg + r] = ssq[ib][r];
            }
            __builtin_amdgcn_s_barrier();
            float* ob = out + ((size_t)b * S_LEN + row0) * EMB_D + h * 128;
            #pragma unroll
            for (int ib = 0; ib < 2; ++ib)
                #pragma unroll
                for (int r = 0; r < 4; ++r) {
                    int il = 32 * wr + 16 * ib + 4 * lg + r;
                    float sst = redL[1][0][il] + redL[1][1][il];
                    float scl = rsqrtf(sst * (1.0f / 128.0f) + 1e-6f) * invn[ib][r];
                    #pragma unroll
                    for (int vf = 0; vf < 4; ++vf) {
                        int d = 64 * wc + 16 * vf + ll;
                        ob[(size_t)il * EMB_D + d] = accO[ib][vf][r] * scl;
                    }
                }
        } else {
            __builtin_amdgcn_s_barrier();   // match g0's barrier
        }
    }
}

extern "C" void kernel_launch(void* const* d_in, const int* in_sizes, int n_in,
                              void* d_out, int out_size, void* d_ws, size_t ws_size,
                              hipStream_t stream) {
    const float* q   = (const float*)d_in[0];
    const float* k   = (const float*)d_in[1];
    const float* v   = (const float*)d_in[2];
    const float* igk = (const float*)d_in[3];
    const float* igb = (const float*)d_in[4];
    const float* fgk = (const float*)d_in[5];
    const float* fgb = (const float*)d_in[6];
    float* out = (float*)d_out;

    char* W = (char*)d_ws;
    ushort_t* Wf   = (ushort_t*)(W);                 //  98304 B
    float* igp_t   = (float*)(W + 98304);            // 131072 B
    float* fgp_t   = (float*)(W + 229376);
    float* a_w     = (float*)(W + 360448);
    float* pm_w    = (float*)(W + 491520);
    float* nf_w    = (float*)(W + 622592);
    ushort_t* Qf   = (ushort_t*)(W + 753664);        // 8 MB each
    ushort_t* Kf   = (ushort_t*)(W + 753664 + 1 * 8388608ull);
    ushort_t* Vt   = (ushort_t*)(W + 753664 + 2 * 8388608ull);  // total ~25.9 MB

    ktransW<<<24, 256, 0, stream>>>(igk, fgk, Wf);
    kprep<<<256, 256, 0, stream>>>(q, k, v, Wf, igb, fgb, Qf, Kf, Vt, igp_t, fgp_t);
    kscan<<<16, 64, 0, stream>>>(igp_t, fgp_t, a_w, pm_w, nf_w);
    kmain<<<256, 512, 0, stream>>>(Qf, Kf, Vt, a_w, pm_w, nf_w, out);
}

// Round 11
// 77.796 us; speedup vs baseline: 1.2444x; 1.2444x over previous
//
#include <hip/hip_runtime.h>

#define S_LEN 2048
#define EMB_D 1024
#define QK_SCALE 0.08838834764831845f  // 1/sqrt(128)
#define RS128 11.313708498984761f      // sqrt(128)
#define LOG2E 1.4426950408889634f

typedef _Float16 f16;
typedef f16 f16x8 __attribute__((ext_vector_type(8)));
typedef float f32x4 __attribute__((ext_vector_type(4)));
typedef unsigned short ushort_t;

typedef const __attribute__((address_space(1))) void gvoid;
typedef __attribute__((address_space(3))) void lvoid;

__device__ __forceinline__ ushort_t f2h(float x) {
    return __builtin_bit_cast(ushort_t, (f16)x);   // RNE
}
__device__ __forceinline__ unsigned pk2h(float a, float b) {
    return __builtin_bit_cast(unsigned, __builtin_amdgcn_cvt_pkrtz(a, b));
}
__device__ __forceinline__ void gl_lds(const void* g, void* l) {
    __builtin_amdgcn_global_load_lds((gvoid*)g, (lvoid*)l, 16, 0, 0);
}

// ---------------- kernel 1: W fp16 B-frag blobs. Wf[ks_g][lane][8], ks_g = src*32+hemb*4+ks.
// q-rows of W scaled by sqrt(128) (compensates QK_SCALE baked into staged q).
__global__ __launch_bounds__(256) void ktransW(const float* __restrict__ igk,
                                               const float* __restrict__ fgk,
                                               ushort_t* __restrict__ Wf) {
    int gid = blockIdx.x * 256 + threadIdx.x;  // 0..6143
    int ks_g = gid >> 6, lane = gid & 63;
    int n = lane & 15, lg = lane >> 4;
    int src = ks_g >> 5, rem = ks_g & 31;
    int hemb = rem >> 2, ks = rem & 3;
    int e0 = src * 1024 + hemb * 128 + ks * 32 + lg * 8;
    float scale = (src == 0) ? RS128 : 1.0f;
    const float* col = (n < 8) ? igk : fgk;
    int nn = n & 7;
    union { ushort_t u[8]; uint4 v4; } P;
    #pragma unroll
    for (int e = 0; e < 8; ++e) P.u[e] = f2h(col[(size_t)(e0 + e) * 8 + nn] * scale);
    *(uint4*)((char*)Wf + ks_g * 1024 + lane * 16) = P.v4;
}

// ---------------- kernel 2: fused split + gate GEMM. Block = (b, 16-row strip), 256 blocks.
// Loads q,k,v rows once; writes pre-swizzled Q/K fp16 tiles, Vt in [tile][joct][128d][8j]
// layout (coalesced B-frag reads later), and computes gate preacts via MFMA from LDS.
__global__ __launch_bounds__(256) void kprep(const float* __restrict__ q,
                                             const float* __restrict__ k,
                                             const float* __restrict__ v,
                                             const ushort_t* __restrict__ Wf,
                                             const float* __restrict__ igb,
                                             const float* __restrict__ fgb,
                                             ushort_t* __restrict__ Qf,
                                             ushort_t* __restrict__ Kf,
                                             ushort_t* __restrict__ Vt,
                                             float* __restrict__ igp_t,
                                             float* __restrict__ fgp_t) {
    __shared__ __align__(16) ushort_t xs[3 * 8 * 16 * 128];  // 96KB [src*8+h][16r][128c] swz
    __shared__ __align__(16) float red[4][64][4];
    const int blk = blockIdx.x;
    const int b = blk >> 7, strip = blk & 127;
    const int s0 = strip * 16;
    const int tile = strip >> 2, subrow = (strip & 3) * 16;
    const int t = threadIdx.x;
    const int w = t >> 6, lane = t & 63;
    const int ll = lane & 15, lg = lane >> 4;

    #pragma unroll
    for (int src = 0; src < 3; ++src) {
        const float* sp = (src == 0 ? q : src == 1 ? k : v) + ((size_t)b * S_LEN + s0) * EMB_D;
        float scale = (src == 0) ? QK_SCALE : 1.0f;
        #pragma unroll
        for (int i = 0; i < 16; ++i) {
            int f = i * 256 + t;
            int r = f >> 8, c4 = f & 255;
            int col = c4 * 4;
            float4 x = *(const float4*)(sp + (size_t)r * EMB_D + col);
            ushort4 H;
            H.x = f2h(x.x * scale); H.y = f2h(x.y * scale);
            H.z = f2h(x.z * scale); H.w = f2h(x.w * scale);
            int hh = col >> 7, d0 = col & 127;
            *(ushort4*)((char*)xs + ((((src * 8 + hh) * 16 + r) * 256 + d0 * 2) ^ ((r & 7) << 4))) = H;
            if (src < 2) {
                char* dst = (char*)(src ? Kf : Qf) + ((size_t)(b * 8 + hh) * 32 + tile) * 16384;
                *(ushort4*)(dst + (((subrow + r) * 256 + d0 * 2) ^ ((r & 7) << 4))) = H;
            }
        }
    }
    __syncthreads();
    // Vt transpose from LDS: [bh][tile][joct][128 d][8 j]
    #pragma unroll
    for (int it = 0; it < 8; ++it) {
        int item = it * 256 + t;           // 0..2047
        int d = item & 127, jo = (item >> 7) & 1, hh = item >> 8;
        union { ushort_t u[8]; uint4 v4; } P;
        #pragma unroll
        for (int e = 0; e < 8; ++e) {
            int r = jo * 8 + e;
            P.u[e] = *(const ushort_t*)((const char*)xs
                       + ((((16 + hh) * 16 + r) * 256 + d * 2) ^ ((r & 7) << 4)));
        }
        char* vd = (char*)Vt + ((size_t)(b * 8 + hh) * 32 + tile) * 16384
                 + ((strip & 3) * 2 + jo) * 2048 + d * 16;
        *(uint4*)vd = P.v4;
    }
    // gate GEMM: wave w does 6 of 24 (src,hemb) rounds; 4-way partial reduce via LDS
    f32x4 acc = {0.f, 0.f, 0.f, 0.f};
    for (int ri = w * 6; ri < w * 6 + 6; ++ri) {
        int src = ri >> 3, hemb = ri & 7;
        #pragma unroll
        for (int ks = 0; ks < 4; ++ks) {
            f16x8 af = *(const f16x8*)((const char*)xs
                        + ((((src * 8 + hemb) * 16 + ll) * 256 + ks * 64 + lg * 16) ^ ((ll & 7) << 4)));
            f16x8 bf = *(const f16x8*)((const char*)Wf + (src * 32 + hemb * 4 + ks) * 1024 + lane * 16);
            acc = __builtin_amdgcn_mfma_f32_16x16x32_f16(af, bf, acc, 0, 0, 0);
        }
    }
    *(f32x4*)&red[w][lane][0] = acc;
    __syncthreads();
    if (w == 0) {
        f32x4 o2 = acc;
        #pragma unroll
        for (int ww = 1; ww < 4; ++ww) o2 += *(const f32x4*)&red[ww][lane][0];
        float bias = (ll < 8) ? igb[ll] : fgb[ll - 8];
        float* dst = (ll < 8) ? igp_t : fgp_t;
        size_t ob = (size_t)(b * 8 + (ll & 7)) * S_LEN + s0 + lg * 4;
        #pragma unroll
        for (int r = 0; r < 4; ++r) dst[ob + r] = o2[r] + bias;
    }
}

// ---------------- kernel 3: per-(b,h) prefix scans, single wave, no barriers.
__global__ __launch_bounds__(64) void kscan(const float* __restrict__ igp_t,
                                            const float* __restrict__ fgp_t,
                                            float* __restrict__ a_w,
                                            float* __restrict__ pm_w,
                                            float* __restrict__ nf_w) {
    const int bh = blockIdx.x;
    const int l = threadIdx.x;
    const int base = bh * S_LEN + l * 32;
    float lf[32];
    #pragma unroll
    for (int i = 0; i < 8; ++i) {
        float4 fg = *(const float4*)(fgp_t + base + i * 4);
        float* p = &lf[i * 4];
        p[0] = fminf(fg.x, 0.f) - log1pf(__expf(-fabsf(fg.x)));
        p[1] = fminf(fg.y, 0.f) - log1pf(__expf(-fabsf(fg.y)));
        p[2] = fminf(fg.z, 0.f) - log1pf(__expf(-fabsf(fg.z)));
        p[3] = fminf(fg.w, 0.f) - log1pf(__expf(-fabsf(fg.w)));
    }
    #pragma unroll
    for (int i = 1; i < 32; ++i) lf[i] += lf[i - 1];
    float tot = lf[31];
    #pragma unroll
    for (int d = 1; d < 64; d <<= 1) {
        float n = __shfl_up(tot, d, 64);
        if (l >= d) tot += n;
    }
    float excl = tot - lf[31];
    float cs[32], a[32];
    #pragma unroll
    for (int i = 0; i < 8; ++i) {
        float4 ig = *(const float4*)(igp_t + base + i * 4);
        float iv[4] = {ig.x, ig.y, ig.z, ig.w};
        #pragma unroll
        for (int e = 0; e < 4; ++e) {
            int idx = i * 4 + e;
            cs[idx] = excl + lf[idx];
            a[idx] = iv[e] - cs[idx];
            a_w[base + idx] = a[idx] * LOG2E;
        }
    }
    float am[32];
    am[0] = a[0];
    #pragma unroll
    for (int i = 1; i < 32; ++i) am[i] = fmaxf(am[i - 1], a[i]);
    float mtot = am[31];
    #pragma unroll
    for (int d = 1; d < 64; d <<= 1) {
        float n = __shfl_up(mtot, d, 64);
        if (l >= d) mtot = fmaxf(mtot, n);
    }
    float exm = __shfl_up(mtot, 1, 64);
    if (l == 0) exm = -INFINITY;
    #pragma unroll
    for (int i = 0; i < 32; ++i) {
        float pmv = fmaxf(exm, am[i]);
        pm_w[base + i] = pmv * LOG2E;
        nf_w[base + i] = __expf(-(cs[i] + pmv));
    }
}

// ---------------- kernel 4: main core. 256 blocks x 512 thr (2 groups x 4 waves).
// R7-proven structure (51.7us, VGPR 112, no spills): K AND V double-buffered in
// LDS via global_load_lds, staged one superstep ahead; a-coeffs in registers.
// V staging is a LINEAR copy from the joct-layout Vt ([joct][128d][8j]); PV
// B-frag read (kk*4+lg)*2048+d*16 is conflict-free (8 lanes/bank-quad, 8 quads).
// Mid-step barrier lgkm-only; vmcnt(0) only at superstep end. Combine phase
// XOR-swizzled (R9: -1.3M bank conflicts).
__global__ __launch_bounds__(512) void kmain(const ushort_t* __restrict__ Qf,
                                             const ushort_t* __restrict__ Kf,
                                             const ushort_t* __restrict__ Vt,
                                             const float* __restrict__ a_w,
                                             const float* __restrict__ pm_w,
                                             const float* __restrict__ nf_w,
                                             float* __restrict__ out) {
    __shared__ __align__(16) ushort_t Kbuf[2][2][8192];  // [group][dbuf] 64KB
    __shared__ __align__(16) ushort_t Vbuf[2][2][8192];  // [group][dbuf] 64KB
    __shared__ __align__(16) ushort_t Csh[2][4096];      // [group] 16KB
    __shared__ float redL[2][2][64];

    const int blk = blockIdx.x;
    const int bh = blk & 15;             // XCD = blk%8 = bh&7 (matches kprep writes)
    const int pair = blk >> 4;           // 0..15
    const int b = bh >> 3, h = bh & 7;
    const int t = threadIdx.x;
    const int w = t >> 6, lane = t & 63;
    const int g = w >> 2, wl = w & 3;
    const int wr = wl >> 1, wc = wl & 1;
    const int lg = lane >> 4, ll = lane & 15;
    const int sw = (ll & 7) << 4;

    const char* q_b = (const char*)Qf + (size_t)bh * 524288;
    const char* k_b = (const char*)Kf + (size_t)bh * 524288;
    const char* v_b = (const char*)Vt + (size_t)bh * 524288;
    const float* aw = a_w + bh * S_LEN;

    float* accX = (float*)&Kbuf[0][0][0];   // 32KB combine region (post-loop alias)
    float* rsX  = (float*)&Csh[0][0];       // 2KB (post-loop alias)

    for (int half = 0; half < 2; ++half) {
        const int rt = half ? (31 - pair) : pair;
        const int row0 = rt * 64;
        const int nss = (rt >> 1) + 1;
        __syncthreads();   // previous half's LDS (incl combine aliases) done

        // Q frags direct from global pre-swizzled tile
        const char* qt = q_b + (size_t)rt * 16384;
        f16x8 qf[2][4];
        #pragma unroll
        for (int ib = 0; ib < 2; ++ib) {
            int row = 32 * wr + 16 * ib + ll;
            #pragma unroll
            for (int kk = 0; kk < 4; ++kk)
                qf[ib][kk] = *(const f16x8*)(qt + ((row * 256 + lg * 16 + kk * 64) ^ ((row & 7) << 4)));
        }
        float pm2[2];
        #pragma unroll
        for (int ib = 0; ib < 2; ++ib)
            pm2[ib] = pm_w[bh * S_LEN + row0 + 32 * wr + 16 * ib + ll];

        // stage K(g), V(g) into buf0 (linear copies); a(g) into regs
        f32x4 avA[2] = {{0.f,0.f,0.f,0.f},{0.f,0.f,0.f,0.f}};
        f32x4 avB[2] = {{0.f,0.f,0.f,0.f},{0.f,0.f,0.f,0.f}};
        if (g <= rt) {
            const char* kt = k_b + (size_t)g * 16384;
            const char* vt = v_b + (size_t)g * 16384;
            #pragma unroll
            for (int i = 0; i < 4; ++i) {
                int o = (wl * 4 + i) * 1024 + lane * 16;
                gl_lds(kt + o, (char*)&Kbuf[g][0][0] + o);
                gl_lds(vt + o, (char*)&Vbuf[g][0][0] + o);
            }
            #pragma unroll
            for (int jb = 0; jb < 2; ++jb)
                avA[jb] = *(const f32x4*)(aw + g * 64 + 32 * wc + 16 * jb + 4 * lg);
        }
        asm volatile("s_waitcnt vmcnt(0)" ::: "memory");
        __builtin_amdgcn_s_barrier();

        f32x4 zero4 = {0.f, 0.f, 0.f, 0.f};
        f32x4 accO[2][4];
        #pragma unroll
        for (int ib = 0; ib < 2; ++ib)
            #pragma unroll
            for (int vf = 0; vf < 4; ++vf) accO[ib][vf] = zero4;
        float rs[2] = {0.f, 0.f};

        for (int ss = 0; ss < nss; ++ss) {
            const int p = ss & 1;
            const int myct = 2 * ss + g;
            const int nxct = myct + 2;
            // issue next-tile staging into buf p^1 (drains at END of this superstep)
            if (nxct <= rt) {
                const char* kt = k_b + (size_t)nxct * 16384;
                const char* vt = v_b + (size_t)nxct * 16384;
                #pragma unroll
                for (int i = 0; i < 4; ++i) {
                    int o = (wl * 4 + i) * 1024 + lane * 16;
                    gl_lds(kt + o, (char*)&Kbuf[g][p ^ 1][0] + o);
                    gl_lds(vt + o, (char*)&Vbuf[g][p ^ 1][0] + o);
                }
                if (p == 0) {
                    #pragma unroll
                    for (int jb = 0; jb < 2; ++jb)
                        avB[jb] = *(const f32x4*)(aw + nxct * 64 + 32 * wc + 16 * jb + 4 * lg);
                } else {
                    #pragma unroll
                    for (int jb = 0; jb < 2; ++jb)
                        avA[jb] = *(const f32x4*)(aw + nxct * 64 + 32 * wc + 16 * jb + 4 * lg);
                }
            }
            const bool act = (myct <= rt);
            if (act) {
                const char* kl = (const char*)&Kbuf[g][p][0];
                f32x4 accST[2][2];
                accST[0][0] = zero4; accST[0][1] = zero4;
                accST[1][0] = zero4; accST[1][1] = zero4;
                __builtin_amdgcn_s_setprio(1);
                #pragma unroll
                for (int kk = 0; kk < 4; ++kk) {
                    f16x8 kf0 = *(const f16x8*)(kl + (((32 * wc + ll) * 256 + lg * 16 + kk * 64) ^ sw));
                    f16x8 kf1 = *(const f16x8*)(kl + (((32 * wc + 16 + ll) * 256 + lg * 16 + kk * 64) ^ sw));
                    accST[0][0] = __builtin_amdgcn_mfma_f32_16x16x32_f16(kf0, qf[0][kk], accST[0][0], 0, 0, 0);
                    accST[0][1] = __builtin_amdgcn_mfma_f32_16x16x32_f16(kf0, qf[1][kk], accST[0][1], 0, 0, 0);
                    accST[1][0] = __builtin_amdgcn_mfma_f32_16x16x32_f16(kf1, qf[0][kk], accST[1][0], 0, 0, 0);
                    accST[1][1] = __builtin_amdgcn_mfma_f32_16x16x32_f16(kf1, qf[1][kk], accST[1][1], 0, 0, 0);
                }
                __builtin_amdgcn_s_setprio(0);
                // epilogue: decay, mask, rowsum, pack fp16, Cs write
                const bool diag = (myct == rt);
                #pragma unroll
                for (int jb = 0; jb < 2; ++jb) {
                    f32x4 av;
                    #pragma unroll
                    for (int r = 0; r < 4; ++r) av[r] = (p == 0) ? avA[jb][r] : avB[jb][r];
                    #pragma unroll
                    for (int ib = 0; ib < 2; ++ib) {
                        int il = 32 * wr + 16 * ib + ll;
                        float cv[4];
                        #pragma unroll
                        for (int r = 0; r < 4; ++r) {
                            int jl = 32 * wc + 16 * jb + 4 * lg + r;
                            float x = accST[jb][ib][r] * exp2f(av[r] - pm2[ib]);
                            if (diag && jl > il) x = 0.f;
                            rs[ib] += x;
                            cv[r] = x;
                        }
                        int off = (il * 128 + (32 * wc + 16 * jb + 4 * lg) * 2) ^ ((il & 7) << 4);
                        uint2 pk2; pk2.x = pk2h(cv[0], cv[1]); pk2.y = pk2h(cv[2], cv[3]);
                        *(uint2*)((char*)&Csh[g][0] + off) = pk2;
                    }
                }
            }
            // LDS-only barrier (vmem prefetches stay in flight)
            asm volatile("s_waitcnt lgkmcnt(0)" ::: "memory");
            __builtin_amdgcn_s_barrier();
            if (act) {
                const char* vl = (const char*)&Vbuf[g][p][0];
                __builtin_amdgcn_s_setprio(1);
                #pragma unroll
                for (int kk = 0; kk < 2; ++kk)
                    #pragma unroll
                    for (int ib = 0; ib < 2; ++ib) {
                        int rowA = 32 * wr + 16 * ib + ll;
                        f16x8 pa = *(const f16x8*)((const char*)&Csh[g][0]
                                                   + ((rowA * 128 + lg * 16 + kk * 64) ^ ((rowA & 7) << 4)));
                        #pragma unroll
                        for (int vf = 0; vf < 4; ++vf) {
                            f16x8 vb2 = *(const f16x8*)(vl + (kk * 4 + lg) * 2048
                                                        + (64 * wc + 16 * vf + ll) * 16);
                            accO[ib][vf] = __builtin_amdgcn_mfma_f32_16x16x32_f16(pa, vb2, accO[ib][vf], 0, 0, 0);
                        }
                    }
                __builtin_amdgcn_s_setprio(0);
            }
            // drain next-tile staging (flew the whole superstep), swap buffers
            asm volatile("s_waitcnt vmcnt(0)" ::: "memory");
            __builtin_amdgcn_s_barrier();
        }

        // ---- combine the two groups' partials, then finalize (group0)
        __syncthreads();
        const int li = wl * 64 + lane;
        const int lsw = (li & 7) << 2;   // float-index XOR swizzle (16B granules)
        if (g == 1) {
            #pragma unroll
            for (int ib = 0; ib < 2; ++ib)
                #pragma unroll
                for (int vf = 0; vf < 4; ++vf)
                    *(f32x4*)&accX[(li * 32 + (ib * 4 + vf) * 4) ^ lsw] = accO[ib][vf];
            rsX[li * 2 + 0] = rs[0];
            rsX[li * 2 + 1] = rs[1];
        }
        __syncthreads();
        if (g == 0) {
            #pragma unroll
            for (int ib = 0; ib < 2; ++ib)
                #pragma unroll
                for (int vf = 0; vf < 4; ++vf)
                    accO[ib][vf] += *(const f32x4*)&accX[(li * 32 + (ib * 4 + vf) * 4) ^ lsw];
            rs[0] += rsX[li * 2 + 0];
            rs[1] += rsX[li * 2 + 1];
            #pragma unroll
            for (int ib = 0; ib < 2; ++ib) {
                rs[ib] += __shfl_xor(rs[ib], 16);
                rs[ib] += __shfl_xor(rs[ib], 32);
            }
            if (lg == 0) {
                redL[0][wc][32 * wr + ll] = rs[0];
                redL[0][wc][32 * wr + 16 + ll] = rs[1];
            }
        }
        __syncthreads();
        if (g == 0) {
            float invn[2][4];
            #pragma unroll
            for (int ib = 0; ib < 2; ++ib)
                #pragma unroll
                for (int r = 0; r < 4; ++r) {
                    int il = 32 * wr + 16 * ib + 4 * lg + r;
                    float tot = redL[0][0][il] + redL[0][1][il];
                    float nf = nf_w[bh * S_LEN + row0 + il];
                    invn[ib][r] = 1.0f / (fmaxf(fabsf(tot), nf) + 1e-6f);
                }
            float ssq[2][4] = {{0.f, 0.f, 0.f, 0.f}, {0.f, 0.f, 0.f, 0.f}};
            #pragma unroll
            for (int ib = 0; ib < 2; ++ib)
                #pragma unroll
                for (int vf = 0; vf < 4; ++vf)
                    #pragma unroll
                    for (int r = 0; r < 4; ++r) {
                        float hv = accO[ib][vf][r] * invn[ib][r];
                        ssq[ib][r] += hv * hv;
                    }
            #pragma unroll
            for (int m = 1; m < 16; m <<= 1)
                #pragma unroll
                for (int ib = 0; ib < 2; ++ib)
                    #pragma unroll
                    for (int r = 0; r < 4; ++r) ssq[ib][r] += __shfl_xor(ssq[ib][r], m);
            if (ll == 0) {
                #pragma unroll
                for (int ib = 0; ib < 2; ++ib)
                    #pragma unroll
                    for (int r = 0; r < 4; ++r)
                        redL[1][wc][32 * wr + 16 * ib + 4 * lg + r] = ssq[ib][r];
            }
            __builtin_amdgcn_s_barrier();
            float* ob = out + ((size_t)b * S_LEN + row0) * EMB_D + h * 128;
            #pragma unroll
            for (int ib = 0; ib < 2; ++ib)
                #pragma unroll
                for (int r = 0; r < 4; ++r) {
                    int il = 32 * wr + 16 * ib + 4 * lg + r;
                    float sst = redL[1][0][il] + redL[1][1][il];
                    float scl = rsqrtf(sst * (1.0f / 128.0f) + 1e-6f) * invn[ib][r];
                    #pragma unroll
                    for (int vf = 0; vf < 4; ++vf) {
                        int d = 64 * wc + 16 * vf + ll;
                        ob[(size_t)il * EMB_D + d] = accO[ib][vf][r] * scl;
                    }
                }
        } else {
            __builtin_amdgcn_s_barrier();   // match g0's barrier
        }
    }
}

extern "C" void kernel_launch(void* const* d_in, const int* in_sizes, int n_in,
                              void* d_out, int out_size, void* d_ws, size_t ws_size,
                              hipStream_t stream) {
    const float* q   = (const float*)d_in[0];
    const float* k   = (const float*)d_in[1];
    const float* v   = (const float*)d_in[2];
    const float* igk = (const float*)d_in[3];
    const float* igb = (const float*)d_in[4];
    const float* fgk = (const float*)d_in[5];
    const float* fgb = (const float*)d_in[6];
    float* out = (float*)d_out;

    char* W = (char*)d_ws;
    ushort_t* Wf   = (ushort_t*)(W);                 //  98304 B
    float* igp_t   = (float*)(W + 98304);            // 131072 B
    float* fgp_t   = (float*)(W + 229376);
    float* a_w     = (float*)(W + 360448);
    float* pm_w    = (float*)(W + 491520);
    float* nf_w    = (float*)(W + 622592);
    ushort_t* Qf   = (ushort_t*)(W + 753664);        // 8 MB each
    ushort_t* Kf   = (ushort_t*)(W + 753664 + 1 * 8388608ull);
    ushort_t* Vt   = (ushort_t*)(W + 753664 + 2 * 8388608ull);  // total ~25.9 MB

    ktransW<<<24, 256, 0, stream>>>(igk, fgk, Wf);
    kprep<<<256, 256, 0, stream>>>(q, k, v, Wf, igb, fgb, Qf, Kf, Vt, igp_t, fgp_t);
    kscan<<<16, 64, 0, stream>>>(igp_t, fgp_t, a_w, pm_w, nf_w);
    kmain<<<256, 512, 0, stream>>>(Qf, Kf, Vt, a_w, pm_w, nf_w, out);
}